// Round 10
// baseline (1427.648 us; speedup 1.0000x reference)
//
#include <hip/hip_runtime.h>
#include <hip/hip_bf16.h>

typedef unsigned short u16;
typedef unsigned int u32;
typedef short bf16x8 __attribute__((ext_vector_type(8)));
typedef float f32x4 __attribute__((ext_vector_type(4)));

#define BAR() asm volatile("s_barrier" ::: "memory")
#define WAITV4() asm volatile("s_waitcnt vmcnt(4)" ::: "memory")
#define WAITV0() asm volatile("s_waitcnt vmcnt(0)" ::: "memory")
#define WAITL() asm volatile("s_waitcnt lgkmcnt(0)" ::: "memory")

// ---------- helpers ----------
__device__ __forceinline__ unsigned pk2(float lo, float hi) {
    unsigned a = (unsigned)__builtin_bit_cast(u16, __float2bfloat16(lo));
    unsigned b = (unsigned)__builtin_bit_cast(u16, __float2bfloat16(hi));
    return a | (b << 16);
}
__device__ __forceinline__ u16 f2bf(float v) {
    return __builtin_bit_cast(u16, __float2bfloat16(v));
}
__device__ __forceinline__ void gl_lds16(const u16* g, u16* l) {
    __builtin_amdgcn_global_load_lds(
        (const __attribute__((address_space(1))) u32*)g,
        (__attribute__((address_space(3))) u32*)l, 16, 0, 0);
}

// ---------- f32 -> bf16 weight convert ----------
__global__ void cvtbf(const float4* __restrict__ s, uint2* __restrict__ d, int n4) {
    int i = blockIdx.x * blockDim.x + threadIdx.x;
    int stride = gridDim.x * blockDim.x;
    for (; i < n4; i += stride) {
        float4 f = s[i];
        uint2 o;
        o.x = pk2(f.x, f.y);
        o.y = pk2(f.z, f.w);
        d[i] = o;
    }
}

// ---------- build x = [u_t | emb[s_i]] as bf16 [65536][1536] ----------
__global__ __launch_bounds__(256) void xbuild(const float* __restrict__ u_t,
                                              const float* __restrict__ emb,
                                              const int* __restrict__ s_i,
                                              u16* __restrict__ xb) {
    const long u = (long)blockIdx.x * blockDim.x + threadIdx.x;
    const int row = (int)(u / 192);
    const int c8 = (int)(u % 192);
    const float* src = (c8 < 96) ? (u_t + (long)row * 768 + c8 * 8)
                                 : (emb + (long)s_i[row] * 768 + (c8 - 96) * 8);
    float4 f0 = ((const float4*)src)[0];
    float4 f1 = ((const float4*)src)[1];
    uint4 o;
    o.x = pk2(f0.x, f0.y);
    o.y = pk2(f0.z, f0.w);
    o.z = pk2(f1.x, f1.y);
    o.w = pk2(f1.z, f1.w);
    *(uint4*)(xb + u * 8) = o;
}

// ---------- GEMM1: 256x256 8-phase (R8-verified), tanh-GELU -> bf16 --------
template <int LDK, int NT, int TN>
__global__ __launch_bounds__(512, 2) void gemm256(
    const u16* __restrict__ Ag, const u16* __restrict__ Bg,
    const float* __restrict__ bias, u16* __restrict__ outb) {
    __shared__ __align__(16) u16 lds[65536];  // 128 KiB

    const int tid = threadIdx.x;
    const int lane = tid & 63;
    const int wv = tid >> 6;
    const int wm = wv >> 2;
    const int wn = wv & 3;

    const int cpx = (int)gridDim.x >> 3;
    const int tile = ((int)blockIdx.x & 7) * cpx + ((int)blockIdx.x >> 3);
    const int tm = tile / TN, tn = tile % TN;
    const long rowBase = (long)tm * 256;
    const long colBase = (long)tn * 256;

    const int srow = tid >> 2;
    const int gch = (tid & 3) ^ ((tid >> 3) & 3);
    const u16* pA = Ag + (rowBase + srow) * (long)LDK + gch * 8;
    const u16* pB = Bg + (colBase + srow) * (long)LDK + gch * 8;
    const int dstBase = wv * 512;

    auto stageA = [&](int kt, int ks, int b) {
        const u16* s = pA + kt * 64 + ks * 32;
        u16* d = lds + b * 32768 + ks * 8192 + dstBase;
        gl_lds16(s, d);
        gl_lds16(s + (long)128 * LDK, d + 4096);
    };
    auto stageB = [&](int kt, int ks, int b) {
        const u16* s = pB + kt * 64 + ks * 32;
        u16* d = lds + b * 32768 + 16384 + ks * 8192 + dstBase;
        gl_lds16(s, d);
        gl_lds16(s + (long)128 * LDK, d + 4096);
    };

    const int l15 = lane & 15, lc = lane >> 4;
    int offA[8], offB[4];
#pragma unroll
    for (int i = 0; i < 8; ++i) {
        int r = wm * 128 + i * 16 + l15;
        offA[i] = r * 32 + ((lc ^ ((r >> 1) & 3)) << 3);
    }
#pragma unroll
    for (int n = 0; n < 4; ++n) {
        int r = wn * 64 + n * 16 + l15;
        offB[n] = r * 32 + ((lc ^ ((r >> 1) & 3)) << 3);
    }

    f32x4 acc[8][4];
    const f32x4 zero = {0.f, 0.f, 0.f, 0.f};
#pragma unroll
    for (int m = 0; m < 8; ++m)
#pragma unroll
        for (int n = 0; n < 4; ++n) acc[m][n] = zero;

    stageA(0, 0, 0);
    stageB(0, 0, 0);
    stageA(0, 1, 0);
    stageB(0, 1, 0);
    WAITV4();
    BAR();

    bf16x8 bA[4], bB[4];
    for (int kt = 0; kt < NT; ++kt) {
        const int b = kt & 1;
        const u16* rA0 = lds + b * 32768;
        const u16* rB0 = rA0 + 16384;
        const u16* rA1 = rA0 + 8192;
        const u16* rB1 = rB0 + 8192;
        const bool pf = (kt + 1 < NT);

        // P0
#pragma unroll
        for (int n = 0; n < 4; ++n) bB[n] = *(const bf16x8*)(rB0 + offB[n]);
#pragma unroll
        for (int m = 0; m < 4; ++m) bA[m] = *(const bf16x8*)(rA0 + offA[m]);
        if (pf) stageA(kt + 1, 0, b ^ 1);
        BAR();
        WAITL();
        __builtin_amdgcn_s_setprio(1);
#pragma unroll
        for (int m = 0; m < 4; ++m)
#pragma unroll
            for (int n = 0; n < 4; ++n)
                acc[m][n] = __builtin_amdgcn_mfma_f32_16x16x32_bf16(bA[m], bB[n], acc[m][n], 0, 0, 0);
        __builtin_amdgcn_s_setprio(0);
        BAR();

        // P1
#pragma unroll
        for (int m = 0; m < 4; ++m) bA[m] = *(const bf16x8*)(rA0 + offA[4 + m]);
        if (pf) stageB(kt + 1, 0, b ^ 1);
        BAR();
        WAITL();
        __builtin_amdgcn_s_setprio(1);
#pragma unroll
        for (int m = 0; m < 4; ++m)
#pragma unroll
            for (int n = 0; n < 4; ++n)
                acc[4 + m][n] = __builtin_amdgcn_mfma_f32_16x16x32_bf16(bA[m], bB[n], acc[4 + m][n], 0, 0, 0);
        __builtin_amdgcn_s_setprio(0);
        if (pf) { WAITV4(); } else { WAITV0(); }
        BAR();

        // P2
#pragma unroll
        for (int n = 0; n < 4; ++n) bB[n] = *(const bf16x8*)(rB1 + offB[n]);
#pragma unroll
        for (int m = 0; m < 4; ++m) bA[m] = *(const bf16x8*)(rA1 + offA[m]);
        if (pf) stageA(kt + 1, 1, b ^ 1);
        BAR();
        WAITL();
        __builtin_amdgcn_s_setprio(1);
#pragma unroll
        for (int m = 0; m < 4; ++m)
#pragma unroll
            for (int n = 0; n < 4; ++n)
                acc[m][n] = __builtin_amdgcn_mfma_f32_16x16x32_bf16(bA[m], bB[n], acc[m][n], 0, 0, 0);
        __builtin_amdgcn_s_setprio(0);
        BAR();

        // P3
#pragma unroll
        for (int m = 0; m < 4; ++m) bA[m] = *(const bf16x8*)(rA1 + offA[4 + m]);
        if (pf) stageB(kt + 1, 1, b ^ 1);
        BAR();
        WAITL();
        __builtin_amdgcn_s_setprio(1);
#pragma unroll
        for (int m = 0; m < 4; ++m)
#pragma unroll
            for (int n = 0; n < 4; ++n)
                acc[4 + m][n] = __builtin_amdgcn_mfma_f32_16x16x32_bf16(bA[m], bB[n], acc[4 + m][n], 0, 0, 0);
        __builtin_amdgcn_s_setprio(0);
        if (pf) { WAITV4(); } else { WAITV0(); }
        BAR();
    }

    const int N = TN * 256;
#pragma unroll
    for (int n = 0; n < 4; ++n) {
        long gc = colBase + wn * 64 + n * 16 + l15;
        float bv = bias[gc];
#pragma unroll
        for (int i = 0; i < 8; ++i) {
            long gr = rowBase + wm * 128 + i * 16 + (lc << 2);
#pragma unroll
            for (int j = 0; j < 4; ++j) {
                float v = acc[i][n][j] + bv;
                float w = v * v;
                float z = v * fmaf(w, -0.0713548162f, -1.5957691216f);  // -2u
                v = __fdividef(v, 1.0f + __expf(z));
                outb[(gr + j) * N + gc] = f2bf(v);
            }
        }
    }
}

// ---------- GEMM2+LN fused: newh = LN(hbuf @ W2^T + b2) -------------------
// BM=64 (full-width rows), BN=768, BK=64, 512 thr / 8 waves (wn 0..7, 96 cols
// each; all waves share the A panel). Single-buffer LDS (A 8K + B 96K),
// 2-barrier loop (staging L2-bound). LN in epilogue -> no y round-trip.
__global__ __launch_bounds__(512, 2) void gemm2ln(
    const u16* __restrict__ hbuf, const u16* __restrict__ w2b,
    const float* __restrict__ b2, const float* __restrict__ gamma,
    const float* __restrict__ beta, float* __restrict__ newh) {
    __shared__ __align__(16) u16 As[4096];    // [64][64]
    __shared__ __align__(16) u16 Bs[49152];   // [768][64]
    __shared__ float redS[8][64];
    __shared__ float redQ[8][64];
    __shared__ float lnMu[64];
    __shared__ float lnInv[64];

    const int tid = threadIdx.x;
    const int lane = tid & 63;
    const int wv = tid >> 6;   // = wn, 0..7
    const int l15 = lane & 15, lc = lane >> 4;
    const long rowBase = (long)blockIdx.x * 64;

    // staging: row = tid>>3 (0..63), chunk = tid&7; src chunk XOR (row&7);
    // LDS dest linear = tid*16B (wave-uniform base wv*512 u16 + lane*16B).
    const int srow = tid >> 3;
    const int sch = (tid & 7) ^ (srow & 7);
    const u16* srcA = hbuf + (rowBase + srow) * 2048 + sch * 8;
    const u16* srcB = w2b + (long)srow * 2048 + sch * 8;

    // fragment offsets (u16 units): row r -> r*64 + ((kk*4+lc)^(r&7))*8;
    // (r&7)==(l15&7) for all frags (row strides are multiples of 8).
    int offA[2][4], offB[2][6];
#pragma unroll
    for (int kk = 0; kk < 2; ++kk) {
#pragma unroll
        for (int i = 0; i < 4; ++i) {
            int r = i * 16 + l15;
            offA[kk][i] = r * 64 + (((kk * 4 + lc) ^ (r & 7)) << 3);
        }
#pragma unroll
        for (int n = 0; n < 6; ++n) {
            int r = wv * 96 + n * 16 + l15;
            offB[kk][n] = r * 64 + (((kk * 4 + lc) ^ (r & 7)) << 3);
        }
    }

    f32x4 acc[4][6];
    const f32x4 zero = {0.f, 0.f, 0.f, 0.f};
#pragma unroll
    for (int i = 0; i < 4; ++i)
#pragma unroll
        for (int n = 0; n < 6; ++n) acc[i][n] = zero;

    for (int kt = 0; kt < 32; ++kt) {
        // stage A (1 pass) + B (12 passes)
        gl_lds16(srcA + kt * 64, As + wv * 512);
#pragma unroll
        for (int p = 0; p < 12; ++p)
            gl_lds16(srcB + (long)p * 131072 + kt * 64, Bs + p * 4096 + wv * 512);
        __syncthreads();  // drains vmcnt: staged data visible
#pragma unroll
        for (int kk = 0; kk < 2; ++kk) {
            bf16x8 aF[4], bF[6];
#pragma unroll
            for (int i = 0; i < 4; ++i) aF[i] = *(const bf16x8*)(As + offA[kk][i]);
#pragma unroll
            for (int n = 0; n < 6; ++n) bF[n] = *(const bf16x8*)(Bs + offB[kk][n]);
#pragma unroll
            for (int i = 0; i < 4; ++i)
#pragma unroll
                for (int n = 0; n < 6; ++n)
                    acc[i][n] = __builtin_amdgcn_mfma_f32_16x16x32_bf16(aF[i], bF[n], acc[i][n], 0, 0, 0);
        }
        __syncthreads();  // all reads done before next overwrite
    }

    // ---- epilogue: bias, row sums, LN, write ----
    float bv[6];
#pragma unroll
    for (int n = 0; n < 6; ++n) bv[n] = b2[wv * 96 + n * 16 + l15];

    // per-thread partials for its 16 rows (i,j): sum over n of v
    float ps[4][4], pq[4][4];
#pragma unroll
    for (int i = 0; i < 4; ++i)
#pragma unroll
        for (int j = 0; j < 4; ++j) {
            float s = 0.f, q = 0.f;
#pragma unroll
            for (int n = 0; n < 6; ++n) {
                float v = acc[i][n][j] + bv[n];
                s += v;
                q += v * v;
            }
            ps[i][j] = s;
            pq[i][j] = q;
        }
    // reduce across l15 (16 lanes share (lc) -> same rows)
#pragma unroll
    for (int off = 1; off < 16; off <<= 1) {
#pragma unroll
        for (int i = 0; i < 4; ++i)
#pragma unroll
            for (int j = 0; j < 4; ++j) {
                ps[i][j] += __shfl_xor(ps[i][j], off, 64);
                pq[i][j] += __shfl_xor(pq[i][j], off, 64);
            }
    }
    if (l15 == 0) {
#pragma unroll
        for (int i = 0; i < 4; ++i)
#pragma unroll
            for (int j = 0; j < 4; ++j) {
                int r = i * 16 + lc * 4 + j;
                redS[wv][r] = ps[i][j];
                redQ[wv][r] = pq[i][j];
            }
    }
    __syncthreads();
    if (tid < 64) {
        float s = 0.f, q = 0.f;
#pragma unroll
        for (int w = 0; w < 8; ++w) { s += redS[w][tid]; q += redQ[w][tid]; }
        float mu = s * (1.f / 768.f);
        float var = q * (1.f / 768.f) - mu * mu;
        lnMu[tid] = mu;
        lnInv[tid] = rsqrtf(var + 1e-5f);
    }
    __syncthreads();

#pragma unroll
    for (int n = 0; n < 6; ++n) {
        int col = wv * 96 + n * 16 + l15;
        float g = gamma[col], bt = beta[col];
#pragma unroll
        for (int i = 0; i < 4; ++i) {
#pragma unroll
            for (int j = 0; j < 4; ++j) {
                int r = i * 16 + lc * 4 + j;
                float v = acc[i][n][j] + bv[n];
                newh[(rowBase + r) * 768 + col] = (v - lnMu[r]) * lnInv[r] * g + bt;
            }
        }
    }
}

// ---------- scatter-add newh into updated ----------
__global__ __launch_bounds__(256) void scatter_add(const float* __restrict__ newh,
                                                   const int* __restrict__ s_i,
                                                   float* __restrict__ upd) {
    const int lane = threadIdx.x & 63;
    const long b = (long)blockIdx.x * 4 + (threadIdx.x >> 6);
    const long s = s_i[b];
#pragma unroll
    for (int i = 0; i < 12; ++i) {
        int c = i * 64 + lane;
        atomicAdd(&upd[s * 768 + c], newh[b * 768 + c]);
    }
}

// ---------- plain float4 copy ----------
__global__ void copy4(const float4* __restrict__ s, float4* __restrict__ d, long n) {
    long i = (long)blockIdx.x * blockDim.x + threadIdx.x;
    long stride = (long)gridDim.x * blockDim.x;
    for (; i < n; i += stride) d[i] = s[i];
}

extern "C" void kernel_launch(void* const* d_in, const int* in_sizes, int n_in,
                              void* d_out, int out_size, void* d_ws, size_t ws_size,
                              hipStream_t stream) {
    const float* u_t = (const float*)d_in[0];
    const int* s_i = (const int*)d_in[1];
    const float* emb = (const float*)d_in[2];
    const float* W1 = (const float*)d_in[3];
    const float* b1 = (const float*)d_in[4];
    const float* W2 = (const float*)d_in[5];
    const float* b2 = (const float*)d_in[6];
    const float* gamma = (const float*)d_in[7];
    const float* beta = (const float*)d_in[8];

    float* out = (float*)d_out;
    float* newh = out;             // [65536,768] f32 new_h_t (outside upd)
    float* upd = out + 50331648L;  // [262144,768] f32 (scratch first, final last)

    // scratch inside upd (all dead before copy4 runs):
    u16* base = (u16*)upd;
    u16* xb = base;                    // [65536,1536] bf16
    u16* w1b = base + 100663296L;      // [2048,1536] bf16
    u16* hbuf = base + 103809024L;     // [65536,2048] bf16
    u16* w2b = base + 238026752L;      // [768,2048] bf16

    cvtbf<<<1024, 256, 0, stream>>>((const float4*)W1, (uint2*)w1b, 786432);
    cvtbf<<<1024, 256, 0, stream>>>((const float4*)W2, (uint2*)w2b, 393216);
    xbuild<<<49152, 256, 0, stream>>>(u_t, emb, s_i, xb);
    // GEMM1: M=65536, N=2048, K=1536 -> 2048 tiles (tanh-GELU, bf16 out)
    gemm256<1536, 24, 8><<<2048, 512, 0, stream>>>(xb, w1b, b1, hbuf);
    // GEMM2 + LN fused: 1024 blocks of 64 rows x 768 cols
    gemm2ln<<<1024, 512, 0, stream>>>(hbuf, w2b, b2, gamma, beta, newh);
    copy4<<<2048, 256, 0, stream>>>((const float4*)emb, (float4*)upd, 50331648L);
    scatter_add<<<16384, 256, 0, stream>>>(newh, s_i, upd);
}